// Round 6
// baseline (248.186 us; speedup 1.0000x reference)
//
#include <hip/hip_runtime.h>
#include <hip/hip_bf16.h>

typedef short short8 __attribute__((ext_vector_type(8)));
typedef float floatx4 __attribute__((ext_vector_type(4)));

#define NGROUP 512
#define RREG 256
#define D 512
#define ROWS 131072
#define FBAR_ELEMS (NGROUP * D)   // 262144

__device__ __forceinline__ unsigned short f2bf(float f) {
    unsigned int u = __float_as_uint(f);
    unsigned int r = (u + 0x7fffu + ((u >> 16) & 1u)) >> 16;
    return (unsigned short)r;
}
__device__ __forceinline__ float bf2f(unsigned short h) {
    return __uint_as_float(((unsigned int)h) << 16);
}
__device__ __forceinline__ float fast_tanh(float x) {
    float cx = fminf(fmaxf(x, -9.5f), 9.5f);
    float e  = __builtin_amdgcn_exp2f(cx * 2.8853900817779268f);  // e^{2cx}
    return (e - 1.f) * __builtin_amdgcn_rcpf(e + 1.f);
}

// ---- kernel 1: W1 fp32 -> bf16, plain row-major [outcol][k] ----
__global__ __launch_bounds__(256) void conv_w1(const float* __restrict__ W1,
                                               unsigned short* __restrict__ W1bf) {
    int i = (blockIdx.x * 256 + threadIdx.x) * 4;
    float4 v = *reinterpret_cast<const float4*>(W1 + i);
    ushort4 o;
    o.x = f2bf(v.x); o.y = f2bf(v.y); o.z = f2bf(v.z); o.w = f2bf(v.w);
    *reinterpret_cast<ushort4*>(W1bf + i) = o;
}

// ---- kernel 2: score GEMM ----
// 2048 blocks x 512 threads (8 waves). Block = 64 rows of x.
// Staging: all 16 HBM loads issued first (MLP), then reduce/pack; bf16(x)
// into swizzled LDS + optional raw-bf16 global copy for the pool kernel.
// GEMM: wave w owns the 64x64 slice cols [w*64,w*64+64); A from LDS,
// B from global (L2-resident W1bf), both double-buffered in registers.
// launch_bounds (512,2): R2/R5 evidence -> compiler allocates ~128 VGPRs
// (64 was too few to pipeline; >128 risks spill).
__global__ __launch_bounds__(512, 2) void score_gemm(
    const float* __restrict__ x, const unsigned short* __restrict__ W1bf,
    const float* __restrict__ b1, const float* __restrict__ W2v,
    float* __restrict__ inv_norm, float* __restrict__ scores,
    unsigned short* __restrict__ xnraw) {

    __shared__ unsigned short A_lds[64 * 512];   // 64 KiB, swizzled
    __shared__ float inv_s[64];
    __shared__ float scorebuf[8][64];            // 2 KiB

    const int t = threadIdx.x;
    const int lane = t & 63;
    const int w = t >> 6;          // wave 0..7
    const int cl = lane & 15;
    const int hi = lane >> 4;
    const size_t row0 = (size_t)blockIdx.x * 64;

    // ---- stage A: wave w owns rows w*8 .. w*8+7; lane covers d = lane*8..+7 ----
    {
        const float* xw = x + (row0 + w * 8) * (size_t)D + lane * 8;
        float4 v[8][2];
        #pragma unroll
        for (int i = 0; i < 8; ++i) {           // 16 independent loads in flight
            v[i][0] = *reinterpret_cast<const float4*>(xw + (size_t)i * D);
            v[i][1] = *reinterpret_cast<const float4*>(xw + (size_t)i * D + 4);
        }
        #pragma unroll
        for (int i = 0; i < 8; ++i) {
            int r = w * 8 + i;
            float4 p = v[i][0], q = v[i][1];
            float ss = p.x*p.x + p.y*p.y + p.z*p.z + p.w*p.w
                     + q.x*q.x + q.y*q.y + q.z*q.z + q.w*q.w;
            #pragma unroll
            for (int m = 1; m < 64; m <<= 1) ss += __shfl_xor(ss, m, 64);
            float inv = 1.0f / fmaxf(sqrtf(ss), 1e-12f);
            if (lane == 0) { inv_s[r] = inv; inv_norm[row0 + r] = inv; }
            short8 pk;
            pk[0] = (short)f2bf(p.x); pk[1] = (short)f2bf(p.y);
            pk[2] = (short)f2bf(p.z); pk[3] = (short)f2bf(p.w);
            pk[4] = (short)f2bf(q.x); pk[5] = (short)f2bf(q.y);
            pk[6] = (short)f2bf(q.z); pk[7] = (short)f2bf(q.w);
            // LDS: 16B slot per lane, XOR-swizzled by row (matches A-frag reads)
            *reinterpret_cast<short8*>(
                (char*)A_lds + r * 1024 + ((lane * 16) ^ ((r & 7) << 4))) = pk;
            if (xnraw)   // raw bf16(x) copy for the pool kernel (coalesced 16B/lane)
                *reinterpret_cast<short8*>(xnraw + (row0 + r) * (size_t)D + lane * 8) = pk;
        }
    }
    __syncthreads();

    // ---- GEMM: K=512 in 16 steps of 32; A/B double-buffered in registers ----
    floatx4 acc[4][4];
    #pragma unroll
    for (int tt = 0; tt < 4; ++tt)
        #pragma unroll
        for (int f = 0; f < 4; ++f) acc[tt][f] = floatx4{0, 0, 0, 0};

    const unsigned short* Bbase = W1bf + ((size_t)(w * 64) << 9);  // cols w*64..
    const int aswz = (cl & 7) << 4;

    short8 bA[4], bB[4], aA[4], aB[4];
    #pragma unroll
    for (int f = 0; f < 4; ++f)
        bA[f] = *reinterpret_cast<const short8*>(Bbase + ((f * 16 + cl) << 9) + hi * 8);
    #pragma unroll
    for (int tt = 0; tt < 4; ++tt)
        aA[tt] = *reinterpret_cast<const short8*>(
            (char*)A_lds + (tt * 16 + cl) * 1024 + ((hi * 16) ^ aswz));

    #pragma unroll
    for (int ks = 0; ks < 16; ++ks) {
        short8* bc = (ks & 1) ? bB : bA;
        short8* ac = (ks & 1) ? aB : aA;
        short8* bn = (ks & 1) ? bA : bB;
        short8* an = (ks & 1) ? aA : aB;
        if (ks < 15) {
            #pragma unroll
            for (int f = 0; f < 4; ++f)
                bn[f] = *reinterpret_cast<const short8*>(
                    Bbase + ((f * 16 + cl) << 9) + (ks + 1) * 32 + hi * 8);
            #pragma unroll
            for (int tt = 0; tt < 4; ++tt)
                an[tt] = *reinterpret_cast<const short8*>(
                    (char*)A_lds + (tt * 16 + cl) * 1024 + ((((ks + 1) * 64) + hi * 16) ^ aswz));
        }
        #pragma unroll
        for (int tt = 0; tt < 4; ++tt)
            #pragma unroll
            for (int f = 0; f < 4; ++f)
                acc[tt][f] = __builtin_amdgcn_mfma_f32_16x16x32_bf16(
                    ac[tt], bc[f], acc[tt][f], 0, 0, 0);
    }

    // ---- epilogue: inv, tanh, w2-dot -> per-row partials for this col-slice ----
    float sp[4][4];
    #pragma unroll
    for (int tt = 0; tt < 4; ++tt)
        #pragma unroll
        for (int i = 0; i < 4; ++i) sp[tt][i] = 0.f;

    #pragma unroll
    for (int f = 0; f < 4; ++f) {
        int col = w * 64 + f * 16 + cl;
        float wv = W2v[col];
        float bb = b1[col];
        #pragma unroll
        for (int tt = 0; tt < 4; ++tt) {
            #pragma unroll
            for (int i = 0; i < 4; ++i) {
                float iv = inv_s[tt * 16 + hi * 4 + i];
                sp[tt][i] += wv * fast_tanh(acc[tt][f][i] * iv + bb);
            }
        }
    }

    #pragma unroll
    for (int tt = 0; tt < 4; ++tt) {
        #pragma unroll
        for (int i = 0; i < 4; ++i) {
            float v = sp[tt][i];
            v += __shfl_xor(v, 1, 64);
            v += __shfl_xor(v, 2, 64);
            v += __shfl_xor(v, 4, 64);
            v += __shfl_xor(v, 8, 64);
            if (cl == 0) scorebuf[w][tt * 16 + hi * 4 + i] = v;
        }
    }
    __syncthreads();

    if (t < 64) {
        float s = 0.f;
        #pragma unroll
        for (int q = 0; q < 8; ++q) s += scorebuf[q][t];
        scores[row0 + t] = s;
    }
}

// ---- kernel 3a: softmax + pooling from raw bf16 x copy ----
// 512 blocks x 512 threads: rh = t>>8 owns half the rows, dp = t&255 owns
// d-pair 2dp; halves combined through LDS.
__global__ __launch_bounds__(512) void softmax_pool_bf16(
    const unsigned short* __restrict__ xnraw, const float* __restrict__ inv_norm,
    const float* __restrict__ scores, float* __restrict__ out) {

    __shared__ float F[RREG];
    __shared__ float wts[RREG];
    __shared__ float pA[256], pB[256];
    const int t = threadIdx.x;
    const int g = blockIdx.x;
    const int rh = t >> 8;
    const int dp = t & 255;

    float s = 0.f, e = 0.f;
    if (t < RREG) { s = scores[g * RREG + t]; F[t] = s; }
    __syncthreads();
    for (int off = 128; off > 0; off >>= 1) {
        if (t < off) F[t] = fmaxf(F[t], F[t + off]);
        __syncthreads();
    }
    float mx = F[0];
    __syncthreads();
    if (t < RREG) { e = expf(s - mx); F[t] = e; }
    __syncthreads();
    for (int off = 128; off > 0; off >>= 1) {
        if (t < off) F[t] += F[t + off];
        __syncthreads();
    }
    float denom = F[0];
    if (t < RREG) {
        float al = e / denom;
        out[FBAR_ELEMS + (size_t)g * RREG + t] = al;          // output 1: alphas
        wts[t] = al * inv_norm[(size_t)g * RREG + t];
    }
    __syncthreads();

    float a0 = 0.f, a1 = 0.f;
    const unsigned short* xb = xnraw + ((size_t)g * RREG + rh * 128) * D + dp * 2;
    #pragma unroll 8
    for (int r = 0; r < 128; ++r) {
        unsigned int u = *reinterpret_cast<const unsigned int*>(xb + (size_t)r * D);
        float wr = wts[rh * 128 + r];
        a0 += wr * bf2f((unsigned short)(u & 0xffffu));
        a1 += wr * bf2f((unsigned short)(u >> 16));
    }
    if (rh == 1) { pA[dp] = a0; pB[dp] = a1; }
    __syncthreads();
    if (rh == 0) {
        float2 o; o.x = a0 + pA[dp]; o.y = a1 + pB[dp];
        *reinterpret_cast<float2*>(out + (size_t)g * D + dp * 2) = o;  // output 0
    }
}

// ---- kernel 3b: fallback pooling from fp32 x (if workspace too small) ----
__global__ __launch_bounds__(512) void softmax_pool_f32(
    const float* __restrict__ x, const float* __restrict__ inv_norm,
    const float* __restrict__ scores, float* __restrict__ out) {

    __shared__ float F[RREG];
    __shared__ float wts[RREG];
    const int t = threadIdx.x;
    const int g = blockIdx.x;

    float s = 0.f, e = 0.f;
    if (t < RREG) { s = scores[g * RREG + t]; F[t] = s; }
    __syncthreads();
    for (int off = 128; off > 0; off >>= 1) {
        if (t < off) F[t] = fmaxf(F[t], F[t + off]);
        __syncthreads();
    }
    float mx = F[0];
    __syncthreads();
    if (t < RREG) { e = expf(s - mx); F[t] = e; }
    __syncthreads();
    for (int off = 128; off > 0; off >>= 1) {
        if (t < off) F[t] += F[t + off];
        __syncthreads();
    }
    float denom = F[0];
    if (t < RREG) {
        float al = e / denom;
        out[FBAR_ELEMS + (size_t)g * RREG + t] = al;
        wts[t] = al * inv_norm[(size_t)g * RREG + t];
    }
    __syncthreads();

    float a = 0.f;
    const float* xb = x + (size_t)g * RREG * D + t;
    #pragma unroll 8
    for (int r = 0; r < RREG; ++r) a += wts[r] * xb[(size_t)r * D];
    out[(size_t)g * D + t] = a;
}

extern "C" void kernel_launch(void* const* d_in, const int* in_sizes, int n_in,
                              void* d_out, int out_size, void* d_ws, size_t ws_size,
                              hipStream_t stream) {
    const float* x  = (const float*)d_in[0];
    const float* W1 = (const float*)d_in[1];
    const float* b1 = (const float*)d_in[2];
    const float* w2 = (const float*)d_in[3];
    // b2 (d_in[4]) shifts all scores uniformly -> softmax-invariant -> unused.
    float* out = (float*)d_out;

    unsigned short* W1bf = (unsigned short*)d_ws;                    // 512 KiB
    float* inv_norm = (float*)((char*)d_ws + 524288);                // 512 KiB
    float* scores   = (float*)((char*)d_ws + 1048576);               // 512 KiB
    const size_t xn_off = 1572864;
    const size_t xn_bytes = (size_t)ROWS * D * 2;                    // 128 MiB
    unsigned short* xnraw = (ws_size >= xn_off + xn_bytes)
        ? (unsigned short*)((char*)d_ws + xn_off) : nullptr;

    conv_w1<<<256, 256, 0, stream>>>(W1, W1bf);
    score_gemm<<<ROWS / 64, 512, 0, stream>>>(x, W1bf, b1, w2, inv_norm, scores, xnraw);
    if (xnraw)
        softmax_pool_bf16<<<NGROUP, 512, 0, stream>>>(xnraw, inv_norm, scores, out);
    else
        softmax_pool_f32<<<NGROUP, 512, 0, stream>>>(x, inv_norm, scores, out);
}